// Round 3
// baseline (9158.980 us; speedup 1.0000x reference)
//
#include <hip/hip_runtime.h>
#include <hip/hip_cooperative_groups.h>

namespace cg = cooperative_groups;

#define N_      800
#define C_      64
#define TRS_    40
#define SPT_    10
#define BUF_    120
#define T_      400
#define STRIDE  528           // per-row history stride in words (520 used, 16B-aligned rows)
#define KPL     13            // edges per lane in the k-grid: 13*64 = 832 >= 800
#define SENT    0x7FC00BADu   // qNaN sentinel for "not yet written"
#define FRESH_D 7             // d < 7  -> fresh list (per-step scalar sc1)
#define MID_D   24            // 7<=d<24 -> mid (per-step scalar sc1, windowed)
                              // d >= 24 -> far (cached float4 windows + sc1 retry)

#define A_F     (-0.5f)
#define OMEGA_F (10.0f)
#define G_F     (500.0f)
#define KGI_F   (5.0f)
#define DT_F    (1e-4f)

#define ALD(p) __hip_atomic_load((p), __ATOMIC_RELAXED, __HIP_MEMORY_SCOPE_AGENT)

// ---------------- prelude kernels ----------------

__global__ void k_sumsq(const float* __restrict__ sc, float* __restrict__ sumsq) {
    __shared__ float sh[4];
    int tid = threadIdx.x;
    int idx = blockIdx.x * 256 + tid;
    float s = 0.f;
    for (int i = idx; i < N_ * N_; i += 256 * 256) { float v = sc[i]; s += v * v; }
    #pragma unroll
    for (int o = 1; o < 64; o <<= 1) s += __shfl_xor(s, o, 64);
    if ((tid & 63) == 0) sh[tid >> 6] = s;
    __syncthreads();
    if (tid == 0) atomicAdd(sumsq, sh[0] + sh[1] + sh[2] + sh[3]);
}

__global__ void k_detect(const int* __restrict__ dw, int* __restrict__ flag) {
    __shared__ int sh[4];
    int tid = threadIdx.x;
    int v = 0;
    for (int idx = 2 * tid + 1; idx < 800; idx += 512) v |= dw[idx];
    #pragma unroll
    for (int o = 1; o < 64; o <<= 1) v |= __shfl_xor(v, o, 64);
    if ((tid & 63) == 0) sh[tid >> 6] = v;
    __syncthreads();
    if (tid == 0) flag[0] = ((sh[0] | sh[1] | sh[2] | sh[3]) == 0) ? 1 : 0; // 1 => int64
}

// linear history: row j, time tau at slot tau+120 (tau in [-120,399])
__global__ void k_init(const float* __restrict__ hE, unsigned int* __restrict__ xh) {
    int idx = blockIdx.x * 256 + threadIdx.x;
    if (idx >= N_ * 520) return;
    int j = idx / 520, s = idx - j * 520;
    unsigned int v = (s < 120) ? __float_as_uint(hE[j * BUF_ + (119 - s)]) : SENT;
    xh[j * STRIDE + s] = v;
}

// ---------------- main persistent kernel ----------------

__global__ void __launch_bounds__(512, 1) k_main(
    const float* __restrict__ sc, const int* __restrict__ dw,
    const float* __restrict__ hx, const float* __restrict__ external,
    const float* __restrict__ noise, const float* __restrict__ lm,
    const float* __restrict__ sumsq, const int* __restrict__ flag,
    unsigned int* __restrict__ xh, float* __restrict__ xtr, float* __restrict__ out)
{
    cg::grid_group grid = cg::this_grid();
    const int lane = threadIdx.x & 63;
    const int i = (int)((blockIdx.x * 512 + threadIdx.x) >> 6); // row 0..799

    const float inv_norm = 1.0f / sqrtf(*sumsq);
    const int is64 = *flag;

    // ---- per-lane edge grid: weights, window bases, phases, class ----
    float w[KPL]; int wb[KPL]; int ph[KPL]; int isfar[KPL];
    float rsum = 0.f;
    #pragma unroll
    for (int k = 0; k < KPL; ++k) {
        int j = k * 64 + lane;
        bool valid = (j < N_);
        int jj = valid ? j : 0;
        int base = i * N_ + jj;
        float wv = valid ? fabsf(sc[base]) * inv_norm : 0.f;
        int dv = valid ? dw[is64 ? (base << 1) : base] : 119;
        rsum += wv;
        if (dv < FRESH_D) { wv = 0.f; dv = 119; }   // edge handled by fresh list
        w[k] = wv;
        if (dv >= MID_D) {
            int p = (-1 - dv) & 3;                  // per-edge constant phase
            ph[k] = p;
            wb[k] = jj * STRIDE + 120 + (-1 - dv - p); // 16B-aligned window base
            isfar[k] = 1;
        } else {
            ph[k] = 0;
            wb[k] = jj * STRIDE + 119 - dv;         // direct window, values = steps
            isfar[k] = 0;
        }
    }
    #pragma unroll
    for (int o = 1; o < 64; o <<= 1) rsum += __shfl_xor(rsum, o, 64);

    // ---- fresh-edge side list (d < 7): uniform scan, round-robin to lanes ----
    float fw0 = 0.f, fw1 = 0.f; int fo0 = 0, fo1 = 0;
    {
        int c = 0;
        for (int e = 0; e < N_; ++e) {
            int be = i * N_ + e;
            int dv = dw[is64 ? (be << 1) : be];
            if (dv < FRESH_D) {
                if ((c & 63) == lane) {
                    float wv = fabsf(sc[be]) * inv_norm;
                    int fo = e * STRIDE + 119 - dv;
                    if (c < 64) { fw0 = wv; fo0 = fo; }
                    else        { fw1 = wv; fo1 = fo; }
                }
                ++c;
            }
        }
    }

    // ---- preload stimulus + noise for all 400 steps into registers ----
    float ue[7], n0r[7], n1r[7];
    #pragma unroll
    for (int q = 0; q < 7; ++q) {
        int tp = q * 64 + lane;
        if (tp < T_) {
            int tr = tp / SPT_, sp = tp - tr * SPT_;
            ue[q]  = external[(i * SPT_ + sp) * TRS_ + tr];
            n0r[q] = noise[(tp * N_ + i) * 2 + 0];
            n1r[q] = noise[(tp * N_ + i) * 2 + 1];
        } else { ue[q] = 0.f; n0r[q] = 0.f; n1r[q] = 0.f; }
    }

    float x = hx[2 * i], y = hx[2 * i + 1];   // uniform across the wave

    int t = 0, tmod = 0;
    #pragma unroll 1
    for (int q = 0; q < 7; ++q) {
        const int nmb = (q == 6) ? 2 : 8;     // miniblocks of 8 steps
        #pragma unroll 1
        for (int mb = 0; mb < nmb; ++mb) {
            const int t0 = t;
            float win[KPL][12];

            // ---- miniblock prologue: gather windows ----
            #pragma unroll
            for (int k = 0; k < KPL; ++k) {
                if (isfar[k]) {
                    const float4* fp = reinterpret_cast<const float4*>(
                        (const float*)xh + wb[k] + t0);
                    float4 a = fp[0], b = fp[1], cq = fp[2];
                    win[k][0]=a.x;  win[k][1]=a.y;  win[k][2]=a.z;  win[k][3]=a.w;
                    win[k][4]=b.x;  win[k][5]=b.y;  win[k][6]=b.z;  win[k][7]=b.w;
                    win[k][8]=cq.x; win[k][9]=cq.y; win[k][10]=cq.z; win[k][11]=cq.w;
                } else {
                    #pragma unroll
                    for (int s2 = 0; s2 < 8; ++s2)
                        win[k][s2] = __uint_as_float(ALD(&xh[wb[k] + t0 + s2]));
                    win[k][8]=0.f; win[k][9]=0.f; win[k][10]=0.f; win[k][11]=0.f;
                }
            }
            // ---- poll: all needed window cells non-sentinel (monotonic cells) ----
            int guard = 0;
            while (true) {
                int pend = 0;
                #pragma unroll
                for (int k = 0; k < KPL; ++k) {
                    #pragma unroll
                    for (int idx = 0; idx < 12; ++idx) {
                        int need = (idx >= ph[k]) & (idx < ph[k] + 8);
                        pend |= need & (__float_as_uint(win[k][idx]) == SENT);
                    }
                }
                if (!__any(pend)) break;
                if (++guard > 200000) break;   // safety valve
                #pragma unroll
                for (int k = 0; k < KPL; ++k) {
                    #pragma unroll
                    for (int idx = 0; idx < 12; ++idx) {
                        int need = (idx >= ph[k]) & (idx < ph[k] + 8);
                        if (need && __float_as_uint(win[k][idx]) == SENT)
                            win[k][idx] = __uint_as_float(ALD(&xh[wb[k] + t0 + idx]));
                    }
                }
            }

            // ---- 8 integration steps from registers ----
            #pragma unroll
            for (int s = 0; s < 8; ++s) {
                if (q == 6 && mb == 1 && s >= 8) break; // (never: 400 = 48*8+... exact)
                unsigned f0 = ALD(&xh[fo0 + t]);
                unsigned f1 = ALD(&xh[fo1 + t]);
                int g2 = 0;
                while (__any((f0 == SENT) | (f1 == SENT))) {
                    if (f0 == SENT) f0 = ALD(&xh[fo0 + t]);
                    if (f1 == SENT) f1 = ALD(&xh[fo1 + t]);
                    if (++g2 > 200000) break;
                }
                float acc = fw0 * __uint_as_float(f0) + fw1 * __uint_as_float(f1);
                #pragma unroll
                for (int k = 0; k < KPL; ++k) {
                    float v01 = (ph[k] & 1) ? win[k][s + 1] : win[k][s + 0];
                    float v23 = (ph[k] & 1) ? win[k][s + 3] : win[k][s + 2];
                    float v   = (ph[k] & 2) ? v23 : v01;    // win[k][ph+s]
                    acc += w[k] * v;
                }
                #pragma unroll
                for (int o = 1; o < 64; o <<= 1) acc += __shfl_xor(acc, o, 64);

                int tt = mb * 8 + s;
                float u  = __shfl(ue[q],  tt, 64);
                float n0 = __shfl(n0r[q], tt, 64);
                float n1 = __shfl(n1r[q], tt, 64);

                float r2 = x * x + y * y;
                float dx = (A_F - r2) * x - OMEGA_F * y + G_F * (acc - rsum * x) + KGI_F * u;
                float dy = (A_F - r2) * y + OMEGA_F * x;
                x = x + DT_F * dx + n0;
                y = y + DT_F * dy + n1;

                if (lane == 0) {
                    __hip_atomic_store(&xh[i * STRIDE + 120 + t], __float_as_uint(x),
                                       __ATOMIC_RELAXED, __HIP_MEMORY_SCOPE_AGENT);
                    if (tmod == SPT_ - 1) xtr[(t / SPT_) * N_ + i] = x;
                }
                tmod = (tmod == SPT_ - 1) ? 0 : tmod + 1;
                ++t;
            }
        }
    }

    grid.sync();   // single barrier: make xtr visible for the epilogue

    // epilogue: out[c*TRS + tr] = 5 * dot(xtr[tr,:], lm[c,:]) - 2
    for (int o = i; o < C_ * TRS_; o += 800) {
        int c = o / TRS_, tr = o - c * TRS_;
        float s = 0.f;
        #pragma unroll
        for (int k = 0; k < KPL; ++k) {
            int n = k * 64 + lane;
            if (n < N_) s += xtr[tr * N_ + n] * lm[c * N_ + n];
        }
        #pragma unroll
        for (int o2 = 1; o2 < 64; o2 <<= 1) s += __shfl_xor(s, o2, 64);
        if (lane == 0) out[o] = 5.0f * s - 2.0f;
    }
}

// ---------------- launch ----------------

extern "C" void kernel_launch(void* const* d_in, const int* in_sizes, int n_in,
                              void* d_out, int out_size, void* d_ws, size_t ws_size,
                              hipStream_t stream) {
    const float* external = (const float*)d_in[0];
    const float* hx       = (const float*)d_in[1];
    const float* hE       = (const float*)d_in[2];
    const float* sc       = (const float*)d_in[3];
    const float* lm       = (const float*)d_in[4];
    const float* noise    = (const float*)d_in[5];
    const int*   delays   = (const int*)  d_in[6];
    float* out = (float*)d_out;

    float*        sumsq = (float*)d_ws;                    // ws[0]
    int*          flag  = (int*)d_ws + 1;                  // ws[1]
    unsigned int* xh    = (unsigned int*)d_ws + 64;        // N_*STRIDE words (16B-aligned)
    float*        xtr   = (float*)(xh + N_ * STRIDE);      // TRS_*N_ floats

    hipMemsetAsync(d_ws, 0, 8, stream);
    k_sumsq<<<256, 256, 0, stream>>>(sc, sumsq);
    k_detect<<<1, 256, 0, stream>>>(delays, flag);
    k_init<<<(N_ * 520 + 255) / 256, 256, 0, stream>>>(hE, xh);

    void* args[] = { (void*)&sc, (void*)&delays, (void*)&hx, (void*)&external,
                     (void*)&noise, (void*)&lm, (void*)&sumsq, (void*)&flag,
                     (void*)&xh, (void*)&xtr, (void*)&out };
    hipLaunchCooperativeKernel((const void*)k_main, dim3(100), dim3(512), args, 0, stream);
}

// Round 5
// 2726.930 us; speedup vs baseline: 3.3587x; 3.3587x over previous
//
#include <hip/hip_runtime.h>
#include <hip/hip_cooperative_groups.h>

namespace cg = cooperative_groups;

#define N_      800
#define C_      64
#define TRS_    40
#define SPT_    10
#define BUF_    120
#define T_      400
#define STRIDE  528           // per-row history stride in words (520 used)
#define KPL     13            // edges per lane: 13*64 = 832 >= 800
#define SENT    0x7FC00BADu   // qNaN sentinel for "not yet written"
#define NEAR_D  15            // d < 15 -> per-step masked sc1; d >= 15 -> far windows

#define A_F     (-0.5f)
#define OMEGA_F (10.0f)
#define G_F     (500.0f)
#define KGI_F   (5.0f)
#define DT_F    (1e-4f)

#define ALD(p)    __hip_atomic_load((p), __ATOMIC_RELAXED, __HIP_MEMORY_SCOPE_AGENT)
#define AST(p,v)  __hip_atomic_store((p), (v), __ATOMIC_RELAXED, __HIP_MEMORY_SCOPE_AGENT)

// ---------------- prelude kernels (unchanged from R2, proven) ----------------

__global__ void k_sumsq(const float* __restrict__ sc, float* __restrict__ sumsq) {
    __shared__ float sh[4];
    int tid = threadIdx.x;
    int idx = blockIdx.x * 256 + tid;
    float s = 0.f;
    for (int i = idx; i < N_ * N_; i += 256 * 256) { float v = sc[i]; s += v * v; }
    #pragma unroll
    for (int o = 1; o < 64; o <<= 1) s += __shfl_xor(s, o, 64);
    if ((tid & 63) == 0) sh[tid >> 6] = s;
    __syncthreads();
    if (tid == 0) atomicAdd(sumsq, sh[0] + sh[1] + sh[2] + sh[3]);
}

__global__ void k_detect(const int* __restrict__ dw, int* __restrict__ flag) {
    __shared__ int sh[4];
    int tid = threadIdx.x;
    int v = 0;
    for (int idx = 2 * tid + 1; idx < 800; idx += 512) v |= dw[idx];
    #pragma unroll
    for (int o = 1; o < 64; o <<= 1) v |= __shfl_xor(v, o, 64);
    if ((tid & 63) == 0) sh[tid >> 6] = v;
    __syncthreads();
    if (tid == 0) flag[0] = ((sh[0] | sh[1] | sh[2] | sh[3]) == 0) ? 1 : 0; // 1 => int64
}

// linear history: row j, time tau at slot tau+120 (tau in [-120,399])
__global__ void k_init(const float* __restrict__ hE, unsigned int* __restrict__ xh) {
    int idx = blockIdx.x * 256 + threadIdx.x;
    if (idx >= N_ * 520) return;
    int j = idx / 520, s = idx - j * 520;
    unsigned int v = (s < 120) ? __float_as_uint(hE[j * BUF_ + (119 - s)]) : SENT;
    xh[j * STRIDE + s] = v;
}

// ---------------- main persistent kernel ----------------

__global__ void __launch_bounds__(512, 1) k_main(
    const float* __restrict__ sc, const int* __restrict__ dw,
    const float* __restrict__ hx, const float* __restrict__ external,
    const float* __restrict__ noise, const float* __restrict__ lm,
    const float* __restrict__ sumsq, const int* __restrict__ flag,
    unsigned int* __restrict__ xh, float* __restrict__ xtr, float* __restrict__ out)
{
    cg::grid_group grid = cg::this_grid();
    const int lane = threadIdx.x & 63;
    const int i = (int)((blockIdx.x * 512 + threadIdx.x) >> 6); // row 0..799

    const float inv_norm = 1.0f / sqrtf(*sumsq);
    const int is64 = *flag;

    // ---- per-lane edge metadata ----
    // near (d<15): wn, an (word addr of tau=-1-d; +t gives tau=t-1-d)
    // far  (d>=15): wf, af (same formula; +t0, phase-align, 20-word window)
    // dummies point at d=119 (always-old, always-valid cells) with weight 0.
    float wn[KPL], wf[KPL]; int an[KPL], af[KPL];
    float rsum = 0.f;
    #pragma unroll
    for (int k = 0; k < KPL; ++k) {
        int j = k * 64 + lane;
        bool valid = (j < N_);
        int jj = valid ? j : 0;
        int base = i * N_ + jj;
        float wv = valid ? fabsf(sc[base]) * inv_norm : 0.f;
        int dv = valid ? dw[is64 ? (base << 1) : base] : 119;
        rsum += wv;
        bool nearc = valid && (dv < NEAR_D);
        bool farc  = valid && (dv >= NEAR_D);
        wn[k] = nearc ? wv : 0.f;
        wf[k] = farc  ? wv : 0.f;
        an[k] = jj * STRIDE + 119 - (nearc ? dv : 119);
        af[k] = jj * STRIDE + 119 - (farc  ? dv : 119);
    }
    #pragma unroll
    for (int o = 1; o < 64; o <<= 1) rsum += __shfl_xor(rsum, o, 64);

    float x = hx[2 * i], y = hx[2 * i + 1];   // uniform across the wave

    #pragma unroll 1
    for (int mb = 0; mb < 25; ++mb) {
        const int t0 = mb * 16;

        // ---- far prologue: one window at a time, accumulate into fps[16] ----
        float fps[16];
        #pragma unroll
        for (int s = 0; s < 16; ++s) fps[s] = 0.f;

        #pragma unroll
        for (int k = 0; k < KPL; ++k) {
            bool fm = (wf[k] != 0.f);
            int a = af[k] + t0;            // word addr needed at s=0
            int p = a & 3;                 // constant per edge (t0 % 4 == 0)
            int A = a - p;                 // 16B-aligned
            float4 q0, q1, q2, q3, q4;
            if (fm) {
                const float4* f4 = reinterpret_cast<const float4*>((const float*)xh + A);
                q0 = f4[0]; q1 = f4[1]; q2 = f4[2]; q3 = f4[3]; q4 = f4[4];
            } else {
                q0 = q1 = q2 = q3 = q4 = make_float4(0.f, 0.f, 0.f, 0.f);
            }
            float win[20] = { q0.x,q0.y,q0.z,q0.w, q1.x,q1.y,q1.z,q1.w,
                              q2.x,q2.y,q2.z,q2.w, q3.x,q3.y,q3.z,q3.w,
                              q4.x,q4.y,q4.z,q4.w };
            // cells are monotonic SENT->value; cached read may be stale-SENT -> sc1 retry
            int g = 0;
            while (true) {
                int pend = 0;
                #pragma unroll
                for (int z = 0; z < 20; ++z)
                    pend |= (int)((z >= p) & (z < p + 16) &
                                  (__float_as_uint(win[z]) == SENT));
                if (!__any(pend)) break;
                if (++g > 1000000) break;   // safety valve (never expected)
                #pragma unroll
                for (int z = 0; z < 20; ++z)
                    if ((z >= p) && (z < p + 16) && __float_as_uint(win[z]) == SENT)
                        win[z] = __uint_as_float(ALD(&xh[A + z]));
            }
            float wk = wf[k];
            #pragma unroll
            for (int s = 0; s < 16; ++s) {  // value = win[p+s] via 3 cndmask
                float v01 = (p & 1) ? win[s + 1] : win[s];
                float v23 = (p & 1) ? win[s + 3] : win[s + 2];
                float v   = (p & 2) ? v23 : v01;
                fps[s] += wk * v;
            }
        }

        // ---- 16 integration steps ----
        #pragma unroll
        for (int s = 0; s < 16; ++s) {
            const int t = t0 + s;
            int tr = (t * 205) >> 11;       // t/10 for t<400
            int sp = t - tr * 10;
            float u  = external[(i * SPT_ + sp) * TRS_ + tr];
            float n0 = noise[(t * N_ + i) * 2 + 0];
            float n1 = noise[(t * N_ + i) * 2 + 1];

            // near gather: exec-masked scattered sc1 loads, poll until non-sentinel
            unsigned vv[KPL];
            #pragma unroll
            for (int k = 0; k < KPL; ++k)
                vv[k] = (wn[k] != 0.f) ? ALD(&xh[an[k] + t]) : 0u;
            int g = 0;
            while (true) {
                int pend = 0;
                #pragma unroll
                for (int k = 0; k < KPL; ++k) pend |= (vv[k] == SENT) ? 1 : 0;
                if (!__any(pend)) break;
                if (++g > 1000000) break;   // safety valve
                #pragma unroll
                for (int k = 0; k < KPL; ++k)
                    if (vv[k] == SENT) vv[k] = ALD(&xh[an[k] + t]);
            }
            float acc = fps[s];
            #pragma unroll
            for (int k = 0; k < KPL; ++k) acc += wn[k] * __uint_as_float(vv[k]);
            #pragma unroll
            for (int o = 1; o < 64; o <<= 1) acc += __shfl_xor(acc, o, 64);

            float r2 = x * x + y * y;
            float dx = (A_F - r2) * x - OMEGA_F * y + G_F * (acc - rsum * x) + KGI_F * u;
            float dy = (A_F - r2) * y + OMEGA_F * x;
            x = x + DT_F * dx + n0;
            y = y + DT_F * dy + n1;

            if (lane == 0) {
                AST(&xh[i * STRIDE + 120 + t], __float_as_uint(x));
                if (sp == SPT_ - 1) xtr[tr * N_ + i] = x;
            }
        }
    }

    grid.sync();   // single barrier: make xtr visible for the epilogue

    // epilogue: out[c*TRS + tr] = 5 * dot(xtr[tr,:], lm[c,:]) - 2
    for (int o = i; o < C_ * TRS_; o += 800) {
        int c = o / TRS_, tr = o - c * TRS_;
        float s = 0.f;
        #pragma unroll
        for (int k = 0; k < KPL; ++k) {
            int n = k * 64 + lane;
            if (n < N_) s += xtr[tr * N_ + n] * lm[c * N_ + n];
        }
        #pragma unroll
        for (int o2 = 1; o2 < 64; o2 <<= 1) s += __shfl_xor(s, o2, 64);
        if (lane == 0) out[o] = 5.0f * s - 2.0f;
    }
}

// ---------------- launch (identical shape to proven R2) ----------------

extern "C" void kernel_launch(void* const* d_in, const int* in_sizes, int n_in,
                              void* d_out, int out_size, void* d_ws, size_t ws_size,
                              hipStream_t stream) {
    const float* external = (const float*)d_in[0];
    const float* hx       = (const float*)d_in[1];
    const float* hE       = (const float*)d_in[2];
    const float* sc       = (const float*)d_in[3];
    const float* lm       = (const float*)d_in[4];
    const float* noise    = (const float*)d_in[5];
    const int*   delays   = (const int*)  d_in[6];
    float* out = (float*)d_out;

    float*        sumsq = (float*)d_ws;                    // ws[0]
    int*          flag  = (int*)d_ws + 1;                  // ws[1]
    unsigned int* xh    = (unsigned int*)d_ws + 64;        // 800*528 words
    float*        xtr   = (float*)(xh + N_ * STRIDE);      // 40*800 floats

    hipMemsetAsync(d_ws, 0, 8, stream);
    k_sumsq<<<256, 256, 0, stream>>>(sc, sumsq);
    k_detect<<<1, 256, 0, stream>>>(delays, flag);
    k_init<<<(N_ * 520 + 255) / 256, 256, 0, stream>>>(hE, xh);

    void* args[] = { (void*)&sc, (void*)&delays, (void*)&hx, (void*)&external,
                     (void*)&noise, (void*)&lm, (void*)&sumsq, (void*)&flag,
                     (void*)&xh, (void*)&xtr, (void*)&out };
    hipLaunchCooperativeKernel((const void*)k_main, dim3(100), dim3(512), args, 0, stream);
}